// Round 1
// baseline (429.903 us; speedup 1.0000x reference)
//
#include <hip/hip_runtime.h>
#include <math.h>

typedef unsigned short u16;
typedef unsigned char u8;
typedef unsigned int u32;
typedef unsigned long long u64;
typedef __bf16 bf16x8 __attribute__((ext_vector_type(8)));
typedef float f32x4 __attribute__((ext_vector_type(4)));

#define NL 41
#define HW 16384

// ws layout (bytes)
#define NHWC_OFF   0            // 8*16384*256 bf16 = 67,108,864
#define WA_OFF     67108864     // 576*64*8 bf16 = 589,824
#define LAB8_OFF   67698688     // 8*16384 u8 = 131,072
#define GHIST_OFF  67829760     // 8*41 int (pad 2048)
#define ISUM_OFF   67831808     // 2*8*41*128 u64 = 671,744 (feat0=fuse, feat1=d)
#define GATES_OFF  68503552     // 2*8*128 f32

__device__ __forceinline__ u16 f2bf(float f) {
    u32 u = __builtin_bit_cast(u32, f);
    u = (u + 0x7FFFu + ((u >> 16) & 1u)) >> 16;
    return (u16)u;
}

__device__ __forceinline__ void glds16(const void* g, void* l) {
    __builtin_amdgcn_global_load_lds(
        (const __attribute__((address_space(1))) void*)g,
        (__attribute__((address_space(3))) void*)l, 16, 0, 0);
}

// fixed-point scale for i64 segment sums: value * 2^32
#define ISUM_SCALE 4294967296.f
#define ISUM_INV   2.3283064365386963e-10f

// ---------------------------------------------------------------------------
// K0a: weight repack -> Wa[(chunk*9+tap)*8+ct][lane][8] bf16 (A-frag lane order)
// Blocks 0..63 also zero ghist + isum (this kernel runs FIRST in the stream).
// ---------------------------------------------------------------------------
__global__ __launch_bounds__(64)
void k_wpack(const float* __restrict__ w, u16* __restrict__ wa,
             int* __restrict__ ghist, u64* __restrict__ isum)
{
    const int bid = (int)blockIdx.x;        // kt*8 + ct, 576 blocks
    const int l = (int)threadIdx.x;
    if (bid == 0) {
        for (int i = l; i < 8 * NL; i += 64) ghist[i] = 0;
    }
    if (bid < 64) {                          // 64 * 1312 = 83,968 = 2*8*41*128
        u64* p = isum + bid * 1312;
        for (int i = l; i < 1312; i += 64) p[i] = 0ull;
    }
    const int kt = bid >> 3, ct = bid & 7;
    const int chunk = kt / 9, tap = kt - chunk * 9;
    const int co = ct * 16 + (l & 15);
    const int cin0 = chunk * 32 + (l >> 4) * 8;
    u16 tmp[8];
#pragma unroll
    for (int j = 0; j < 8; ++j)
        tmp[j] = f2bf(w[((size_t)co * 256 + cin0 + j) * 9 + tap]);
    *(f32x4*)&wa[((size_t)bid * 64 + l) * 8] = *(f32x4*)tmp;
}

// ---------------------------------------------------------------------------
// K0b: fused add/mul -> bf16 NHWC [b][px][c'] (c'<128 = r+d, 128+c = r*sig(d)).
// Also: nearest-sample labels -> lab8, per-block hist -> ghist, AND the
// d-feature segment sums (column-per-thread LDS bins, race/conflict-free)
// flushed as i64 fixed-point global atomics. 512 blocks (8b x 64 chunks of
// 256 px), 256 thr, 4 subtiles of 64 px reusing the 32 KB staging buffer.
// ---------------------------------------------------------------------------
__global__ __launch_bounds__(256, 2)
void k_prep(const float* __restrict__ r, const float* __restrict__ d,
            const int* __restrict__ label, u16* __restrict__ nhwc,
            u8* __restrict__ lab8, int* __restrict__ ghist,
            u64* __restrict__ isum_d)
{
    __shared__ u16 s[64 * 256];             // [px][c'] 32 KB
    __shared__ float binsd[NL * 256];       // 41,984 B, column tid = (half,c)
    __shared__ int hist[NL];
    __shared__ u8 s_lab[256];
    const int bid = (int)blockIdx.x;
    const int b = bid >> 6;
    const int px0 = (bid & 63) * 256;
    const int tid = (int)threadIdx.x;
    const int c = tid & 127;
    const int half = tid >> 7;

    if (tid < NL) hist[tid] = 0;
    for (int i = tid; i < NL * 64; i += 256) ((f32x4*)binsd)[i] = f32x4{0,0,0,0};
    __syncthreads();

    {
        int px = px0 + tid;
        int yy = px >> 7, xx = px & 127;
        int lab = label[(size_t)b * 512 * 512 + (yy * 4) * 512 + xx * 4];
        lab8[b * HW + px] = (u8)lab;
        s_lab[tid] = (u8)lab;
        atomicAdd(&hist[lab], 1);
    }
    __syncthreads();                        // s_lab ready for bin indexing

    for (int t = 0; t < 4; ++t) {
        const int pxb = px0 + t * 64 + half * 32;
        const float* rp = r + ((size_t)(b * 128 + c)) * HW + pxb;
        const float* dp = d + ((size_t)(b * 128 + c)) * HW + pxb;
        // this thread's 32 labels, hoisted to registers (2 x ds_read_b128)
        const u8* lp = &s_lab[t * 64 + half * 32];
        uint4 lw0 = *(const uint4*)lp;
        uint4 lw1 = *(const uint4*)(lp + 16);
        u32 lwords[8] = {lw0.x, lw0.y, lw0.z, lw0.w, lw1.x, lw1.y, lw1.z, lw1.w};
#pragma unroll
        for (int j = 0; j < 8; ++j) {
            float4 rv = *(const float4*)(rp + j * 4);
            float4 dv = *(const float4*)(dp + j * 4);
            float ra[4] = {rv.x, rv.y, rv.z, rv.w};
            float da[4] = {dv.x, dv.y, dv.z, dv.w};
#pragma unroll
            for (int i = 0; i < 4; ++i) {
                int pxl = half * 32 + j * 4 + i;
                s[pxl * 256 + c] = f2bf(ra[i] + da[i]);
                s[pxl * 256 + 128 + c] = f2bf(ra[i] / (1.f + __expf(-da[i])));
                int lab = (int)((lwords[j] >> (i * 8)) & 0xffu);
                binsd[lab * 256 + tid] += da[i];   // own column: no race
            }
        }
        __syncthreads();
        const f32x4* sf = (const f32x4*)s;
        f32x4* dst = (f32x4*)nhwc + ((size_t)b * HW + px0 + t * 64) * 32;
#pragma unroll
        for (int k = 0; k < 8; ++k) {
            int fi = k * 256 + tid;
            dst[fi] = sf[fi];
        }
        __syncthreads();                    // protect s before next subtile
    }
    // flush d bins -> i64 fixed-point global atomics
    for (int i = tid; i < NL * 128; i += 256) {
        int lab = i >> 7, cc = i & 127;
        float v = binsd[lab * 256 + cc] + binsd[lab * 256 + 128 + cc];
        if (v != 0.f) {
            long long q = (long long)(v * ISUM_SCALE);
            atomicAdd(&isum_d[(b * NL + lab) * 128 + cc], (u64)q);
        }
    }
    if (tid < NL && hist[tid] > 0) atomicAdd(&ghist[b * NL + tid], hist[tid]);
}

// ---------------------------------------------------------------------------
// K1: conv3x3 implicit GEMM, bf16 MFMA 16x16x32, double-buffered LDS.
// Block: 2 rows x 128 px x 128 co; 4 waves (wr,wc), wave tile 64co x 128px.
// grid 512, bid = rowpair*8 + b. Main loop unchanged.
// NEW epilogue: per-block fuse segment sums binned into s_in (dead after the
// last chunk), flushed as i64 fixed-point global atomics -> kills k_seg.
// ---------------------------------------------------------------------------
__global__ __launch_bounds__(256, 2)
void k_conv(const u16* __restrict__ nhwc, const u16* __restrict__ wa,
            const u8* __restrict__ lab8, float* __restrict__ out,
            u64* __restrict__ isum_f)
{
    __shared__ u16 s_in[2 * 2080 * 8];      // 2 x 33280 B
    __shared__ u8 s_lab[256];
    const int tid = (int)threadIdx.x;
    const int bid = (int)blockIdx.x;
    const int b = bid & 7;
    const int y0 = (bid >> 3) * 2;
    const int l = tid & 63;
    const int wv = tid >> 6;
    const int wr = wv & 1;                  // image row within pair
    const int wc = wv >> 1;                 // co half
    const int l15 = l & 15;
    const int l16 = l >> 4;

    {   // zero BOTH buffers once; halo granules stay zero forever
        f32x4 zz = {0.f, 0.f, 0.f, 0.f};
        for (int i = tid; i < 4160; i += 256) ((f32x4*)s_in)[i] = zz;
    }
    s_lab[tid] = lab8[b * HW + y0 * 128 + tid];   // this block's 256 px labels

    // per-lane global byte offsets for 9 staging rounds (-1 = halo/masked)
    int goff[9];
#pragma unroll
    for (int it = 0; it < 9; ++it) {
        int s = it * 256 + tid;
        int row = s / 520;                  // 130 xslots * 4 ci8
        int rem = s - row * 520;
        int xslot = rem >> 2;
        int ci8 = rem & 3;
        int gy = y0 - 1 + row;
        int gx = xslot - 1;
        bool valid = (s < 2080) && ((unsigned)gy < 128u) && ((unsigned)gx < 128u);
        goff[it] = valid ? (((gy << 7) | gx) * 256 + ci8 * 8) * 2 : -1;
    }

    f32x4 acc[4][8];
#pragma unroll
    for (int i = 0; i < 4; ++i)
#pragma unroll
        for (int j = 0; j < 8; ++j) {
            f32x4 zz = {0.f, 0.f, 0.f, 0.f};
            acc[i][j] = zz;
        }

    const char* src_b = (const char*)(nhwc + (size_t)b * HW * 256);
    const int lane_base = (tid & 192) * 16;     // wave-uniform LDS base
    const f32x4* wa4 = (const f32x4*)wa;

    __syncthreads();                         // order zero ds_writes before glds
#pragma unroll
    for (int it = 0; it < 9; ++it)           // stage chunk 0 -> buf 0
        if (goff[it] >= 0)
            glds16(src_b + goff[it], (char*)s_in + it * 4096 + lane_base);

#pragma unroll 1
    for (int chunk = 0; chunk < 8; ++chunk) {
        __syncthreads();                     // publishes stage(chunk), frees other buf

        // A prefetch (taps 0,1) BEFORE next staging -> older in vmcnt FIFO
        f32x4 a0[4], a1[4];
        {
            int kt8 = chunk * 72;
#pragma unroll
            for (int i = 0; i < 4; ++i) a0[i] = wa4[(kt8 + wc * 4 + i) * 64 + l];
#pragma unroll
            for (int i = 0; i < 4; ++i) a1[i] = wa4[(kt8 + 8 + wc * 4 + i) * 64 + l];
        }
        if (chunk < 7) {                     // stage chunk+1 into other buffer
            char* dstb = (char*)s_in + ((chunk + 1) & 1) * 33280 + lane_base;
#pragma unroll
            for (int it = 0; it < 9; ++it)
                if (goff[it] >= 0)
                    glds16(src_b + goff[it] + (chunk + 1) * 64, dstb + it * 4096);
        }

        const char* bufp = (const char*)s_in + (chunk & 1) * 33280;
#pragma unroll
        for (int tap = 0; tap < 9; ++tap) {
            f32x4 aC[4];
#pragma unroll
            for (int i = 0; i < 4; ++i) aC[i] = a0[i];
#pragma unroll
            for (int i = 0; i < 4; ++i) a0[i] = a1[i];
            if (tap + 2 < 9) {
                int kt8 = chunk * 72 + (tap + 2) * 8;
#pragma unroll
                for (int i = 0; i < 4; ++i)
                    a1[i] = wa4[(kt8 + wc * 4 + i) * 64 + l];
            }
            const int rowi = wr + tap / 3;
            const int dxo = tap % 3;
            f32x4 bf[8];
#pragma unroll
            for (int p = 0; p < 8; ++p) {
                int e = (rowi * 130 + p * 16 + l15 + dxo) * 64 + l16 * 16;
                bf[p] = *(const f32x4*)(bufp + e);
            }
#pragma unroll
            for (int ct = 0; ct < 4; ++ct) {
                bf16x8 av = __builtin_bit_cast(bf16x8, aC[ct]);
#pragma unroll
                for (int p = 0; p < 8; ++p)
                    acc[ct][p] = __builtin_amdgcn_mfma_f32_16x16x32_bf16(
                        av, __builtin_bit_cast(bf16x8, bf[p]), acc[ct][p], 0, 0, 0);
            }
        }
    }

    // D: col = px = l&15, row = co = (l>>4)*4 + reg
    const int y = y0 + wr;
    float* outb = out + (size_t)b * 128 * HW + (size_t)y * 128;
#pragma unroll
    for (int ct = 0; ct < 4; ++ct)
#pragma unroll
        for (int p = 0; p < 8; ++p) {
            int x = p * 16 + l15;
#pragma unroll
            for (int rr = 0; rr < 4; ++rr) {
                int co = wc * 64 + ct * 16 + l16 * 4 + rr;
                outb[(size_t)co * HW + x] = acc[ct][p][rr];
            }
        }

    // ---- fuse segment-sum epilogue: reuse s_in (dead) as bins[41][133] ----
    __syncthreads();                         // all waves done reading s_in
    float* binsf = (float*)s_in;             // 41*133*4 = 21,812 B <= 66,560
    for (int i = tid; i < NL * 133; i += 256) binsf[i] = 0.f;
    __syncthreads();
#pragma unroll
    for (int ct = 0; ct < 4; ++ct)
#pragma unroll
        for (int p = 0; p < 8; ++p) {
            int lab = (int)s_lab[wr * 128 + p * 16 + l15];
            float* bp = &binsf[lab * 133 + wc * 64 + ct * 16 + l16 * 4];
#pragma unroll
            for (int rr = 0; rr < 4; ++rr)
                atomicAdd(bp + rr, acc[ct][p][rr]);
        }
    __syncthreads();
    for (int i = tid; i < NL * 128; i += 256) {
        int lab = i >> 7, cc = i & 127;
        float v = binsf[lab * 133 + cc];
        if (v != 0.f) {
            long long q = (long long)(v * ISUM_SCALE);
            atomicAdd(&isum_f[(b * NL + lab) * 128 + cc], (u64)q);
        }
    }
}

// ---------------------------------------------------------------------------
// K3: mean/base select + L2-normalize over classes + SE MLP -> gates.
// Reads i64 fixed-point sums (isum[feat][b][lab][c]).
// ---------------------------------------------------------------------------
__global__ __launch_bounds__(128)
void k_gates(const u64* __restrict__ isum, const int* __restrict__ ghist,
             const float* __restrict__ base_f, const float* __restrict__ base_d,
             const float* __restrict__ f_w1, const float* __restrict__ f_w2,
             const float* __restrict__ d_w1, const float* __restrict__ d_w2,
             float* __restrict__ gates)
{
    __shared__ float sv[128];
    __shared__ float h1[8];
    const int b = (int)blockIdx.x >> 1;
    const int feat = (int)blockIdx.x & 1;
    const int c = (int)threadIdx.x;

    const float* base = feat ? base_d : base_f;
    float suma = 0.f, sumsq = 0.f;
    for (int lc = 0; lc < NL; ++lc) {
        long long q = (long long)isum[((size_t)(feat * 8 + b) * NL + lc) * 128 + c];
        float s = (float)q * ISUM_INV;
        int cnt = ghist[b * NL + lc];
        float att = (cnt > 0) ? (s / (float)cnt) : base[(b * NL + lc) * 128 + c];
        suma += att;
        sumsq += att * att;
    }
    sv[c] = suma / fmaxf(sqrtf(sumsq), 1e-12f);
    __syncthreads();

    const float* w1 = feat ? d_w1 : f_w1;
    const float* w2 = feat ? d_w2 : f_w2;
    if (c < 8) {
        float h = 0.f;
        for (int k = 0; k < 128; ++k) h += w1[c * 128 + k] * sv[k];
        h1[c] = fmaxf(h, 0.f);
    }
    __syncthreads();

    float gv = 0.f;
#pragma unroll
    for (int o = 0; o < 8; ++o) gv += w2[c * 8 + o] * h1[o];
    gates[feat * 1024 + b * 128 + c] = 1.f / (1.f + expf(-gv));
}

// ---------------------------------------------------------------------------
// K4: out = fuse * g_f + d * g_d (fuse in-place in d_out).
// ---------------------------------------------------------------------------
__global__ __launch_bounds__(256)
void k_final(const float* __restrict__ d, const float* __restrict__ gates,
             float* out)
{
    size_t t4 = (size_t)blockIdx.x * 256 + threadIdx.x;
    size_t basei = t4 * 4;
    int bc = (int)(basei >> 14);
    float gf = gates[bc];
    float gd = gates[1024 + bc];
    float4 f = *(const float4*)(out + basei);
    float4 dv = *(const float4*)(d + basei);
    float4 o;
    o.x = f.x * gf + dv.x * gd;
    o.y = f.y * gf + dv.y * gd;
    o.z = f.z * gf + dv.z * gd;
    o.w = f.w * gf + dv.w * gd;
    *(float4*)(out + basei) = o;
}

extern "C" void kernel_launch(void* const* d_in, const int* in_sizes, int n_in,
                              void* d_out, int out_size, void* d_ws, size_t ws_size,
                              hipStream_t stream)
{
    (void)in_sizes; (void)n_in; (void)out_size; (void)ws_size;
    const float* r      = (const float*)d_in[0];
    const float* d      = (const float*)d_in[1];
    const int*   label  = (const int*)d_in[2];
    const float* conv_w = (const float*)d_in[3];
    const float* f_w1   = (const float*)d_in[4];
    const float* f_w2   = (const float*)d_in[5];
    const float* d_w1   = (const float*)d_in[6];
    const float* d_w2   = (const float*)d_in[7];
    const float* base_f = (const float*)d_in[8];
    const float* base_d = (const float*)d_in[9];
    float* out = (float*)d_out;

    char* ws = (char*)d_ws;
    u16* nhwc    = (u16*)(ws + NHWC_OFF);
    u16* wa      = (u16*)(ws + WA_OFF);
    u8*  lab8    = (u8*)(ws + LAB8_OFF);
    int* ghist   = (int*)(ws + GHIST_OFF);
    u64* isum    = (u64*)(ws + ISUM_OFF);        // [2][8][41][128]
    u64* isum_f  = isum;                         // feat 0 = fuse
    u64* isum_d  = isum + 8 * NL * 128;          // feat 1 = d
    float* gates = (float*)(ws + GATES_OFF);

    hipLaunchKernelGGL(k_wpack, dim3(576), dim3(64), 0, stream, conv_w, wa,
                       ghist, isum);
    hipLaunchKernelGGL(k_prep, dim3(512), dim3(256), 0, stream, r, d, label,
                       nhwc, lab8, ghist, isum_d);
    hipLaunchKernelGGL(k_conv, dim3(512), dim3(256), 0, stream, nhwc, wa,
                       lab8, out, isum_f);
    hipLaunchKernelGGL(k_gates, dim3(16), dim3(128), 0, stream, isum, ghist,
                       base_f, base_d, f_w1, f_w2, d_w1, d_w2, gates);
    hipLaunchKernelGGL(k_final, dim3(16384), dim3(256), 0, stream, d, gates, out);
}

// Round 2
// 428.776 us; speedup vs baseline: 1.0026x; 1.0026x over previous
//
#include <hip/hip_runtime.h>
#include <math.h>

typedef unsigned short u16;
typedef unsigned char u8;
typedef unsigned int u32;
typedef unsigned long long u64;
typedef __bf16 bf16x8 __attribute__((ext_vector_type(8)));
typedef float f32x4 __attribute__((ext_vector_type(4)));

#define NL 41
#define HW 16384

// ws layout (bytes)
#define NHWC_OFF   0            // 8*16384*256 bf16 = 67,108,864
#define WA_OFF     67108864     // 576*64*8 bf16 = 589,824 -> 67,698,688
#define LAB8_OFF   67698688     // 8*16384 u8 = 131,072 -> 67,829,760
#define GHIST_OFF  67829760     // 8*41 int (pad to 4096) -> 67,833,856
#define SUMS_OFF   67833856     // 2*8*41*128 f32 = 335,872 -> 68,169,728
#define GATES_OFF  68169728     // 2*8*128 f32 = 8,192 -> 68,177,920
#define PF_OFF     68177920     // OPTIONAL: 512*5248 f32 = 10,747,904 -> 78,925,824
#define PF_END     78925824ull

// per-block partial segment-sum size (floats)
#define PSZ 5248                // 41*128

__device__ __forceinline__ u16 f2bf(float f) {
    u32 u = __builtin_bit_cast(u32, f);
    u = (u + 0x7FFFu + ((u >> 16) & 1u)) >> 16;
    return (u16)u;
}

__device__ __forceinline__ void glds16(const void* g, void* l) {
    __builtin_amdgcn_global_load_lds(
        (const __attribute__((address_space(1))) void*)g,
        (__attribute__((address_space(3))) void*)l, 16, 0, 0);
}

// ---------------------------------------------------------------------------
// K0a: weight repack -> Wa[(chunk*9+tap)*8+ct][lane][8] bf16 (A-frag lane order)
// Block 0 zeroes ghist.
// ---------------------------------------------------------------------------
__global__ __launch_bounds__(64)
void k_wpack(const float* __restrict__ w, u16* __restrict__ wa,
             int* __restrict__ ghist)
{
    const int bid = (int)blockIdx.x;        // kt*8 + ct, 576 blocks
    const int l = (int)threadIdx.x;
    if (bid == 0) {
        for (int i = l; i < 8 * NL; i += 64) ghist[i] = 0;
    }
    const int kt = bid >> 3, ct = bid & 7;
    const int chunk = kt / 9, tap = kt - chunk * 9;
    const int co = ct * 16 + (l & 15);
    const int cin0 = chunk * 32 + (l >> 4) * 8;
    u16 tmp[8];
#pragma unroll
    for (int j = 0; j < 8; ++j)
        tmp[j] = f2bf(w[((size_t)co * 256 + cin0 + j) * 9 + tap]);
    *(f32x4*)&wa[((size_t)bid * 64 + l) * 8] = *(f32x4*)tmp;
}

// ---------------------------------------------------------------------------
// K0b: fused add/mul -> bf16 NHWC; labels -> lab8; hist -> ghist; d-feature
// segment bins (column-per-thread, race/conflict-free) flushed NON-atomically
// to per-block partials pd[bid][41][128] (pd lives in d_out scratch).
// 512 blocks = 8 b x 64 chunks of 256 px.
// ---------------------------------------------------------------------------
__global__ __launch_bounds__(256, 2)
void k_prep(const float* __restrict__ r, const float* __restrict__ d,
            const int* __restrict__ label, u16* __restrict__ nhwc,
            u8* __restrict__ lab8, int* __restrict__ ghist,
            float* __restrict__ pd)
{
    __shared__ u16 s[64 * 256];             // [px][c'] 32 KB
    __shared__ float binsd[NL * 256];       // 41,984 B, column tid = (half,c)
    __shared__ int hist[NL];
    __shared__ u8 s_lab[256];
    const int bid = (int)blockIdx.x;
    const int b = bid >> 6;
    const int px0 = (bid & 63) * 256;
    const int tid = (int)threadIdx.x;
    const int c = tid & 127;
    const int half = tid >> 7;

    if (tid < NL) hist[tid] = 0;
    for (int i = tid; i < NL * 64; i += 256) ((f32x4*)binsd)[i] = f32x4{0,0,0,0};
    __syncthreads();

    {
        int px = px0 + tid;
        int yy = px >> 7, xx = px & 127;
        int lab = label[(size_t)b * 512 * 512 + (yy * 4) * 512 + xx * 4];
        lab8[b * HW + px] = (u8)lab;
        s_lab[tid] = (u8)lab;
        atomicAdd(&hist[lab], 1);
    }
    __syncthreads();                        // s_lab ready for bin indexing

    for (int t = 0; t < 4; ++t) {
        const int pxb = px0 + t * 64 + half * 32;
        const float* rp = r + ((size_t)(b * 128 + c)) * HW + pxb;
        const float* dp = d + ((size_t)(b * 128 + c)) * HW + pxb;
        const u8* lp = &s_lab[t * 64 + half * 32];
        uint4 lw0 = *(const uint4*)lp;
        uint4 lw1 = *(const uint4*)(lp + 16);
        u32 lwords[8] = {lw0.x, lw0.y, lw0.z, lw0.w, lw1.x, lw1.y, lw1.z, lw1.w};
#pragma unroll
        for (int j = 0; j < 8; ++j) {
            float4 rv = *(const float4*)(rp + j * 4);
            float4 dv = *(const float4*)(dp + j * 4);
            float ra[4] = {rv.x, rv.y, rv.z, rv.w};
            float da[4] = {dv.x, dv.y, dv.z, dv.w};
#pragma unroll
            for (int i = 0; i < 4; ++i) {
                int pxl = half * 32 + j * 4 + i;
                s[pxl * 256 + c] = f2bf(ra[i] + da[i]);
                s[pxl * 256 + 128 + c] = f2bf(ra[i] / (1.f + __expf(-da[i])));
                int lab = (int)((lwords[j] >> (i * 8)) & 0xffu);
                binsd[lab * 256 + tid] += da[i];   // own column: no race
            }
        }
        __syncthreads();
        const f32x4* sf = (const f32x4*)s;
        f32x4* dst = (f32x4*)nhwc + ((size_t)b * HW + px0 + t * 64) * 32;
#pragma unroll
        for (int k = 0; k < 8; ++k) {
            int fi = k * 256 + tid;
            dst[fi] = sf[fi];
        }
        __syncthreads();                    // protect s before next subtile
    }
    // flush d bins -> per-block partials (coalesced, non-atomic)
    float* pout = pd + (size_t)bid * PSZ;
    for (int i = tid; i < NL * 128; i += 256) {
        int lab = i >> 7, cc = i & 127;
        pout[i] = binsd[lab * 256 + cc] + binsd[lab * 256 + 128 + cc];
    }
    if (tid < NL && hist[tid] > 0) atomicAdd(&ghist[b * NL + tid], hist[tid]);
}

// ---------------------------------------------------------------------------
// K1: conv3x3 implicit GEMM (main loop = round-0 proven structure).
// EP=1: epilogue bins fuse acc into s_in (dead), stride-129 rows for bank
// spread, split per-wr to cut atomic collisions, then writes per-block
// partials pf[bid][41][128] non-atomically.  EP=0: round-0 behavior.
// ---------------------------------------------------------------------------
template<int EP>
__global__ __launch_bounds__(256, 2)
void k_conv(const u16* __restrict__ nhwc, const u16* __restrict__ wa,
            const u8* __restrict__ lab8, float* __restrict__ out,
            float* __restrict__ pf)
{
    __shared__ u16 s_in[2 * 2080 * 8];      // 2 x 33280 B
    __shared__ u8 s_lab[256];
    const int tid = (int)threadIdx.x;
    const int bid = (int)blockIdx.x;
    const int b = bid & 7;
    const int y0 = (bid >> 3) * 2;
    const int l = tid & 63;
    const int wv = tid >> 6;
    const int wr = wv & 1;                  // image row within pair
    const int wc = wv >> 1;                 // co half
    const int l15 = l & 15;
    const int l16 = l >> 4;

    {   // zero BOTH buffers once; halo granules stay zero forever
        f32x4 zz = {0.f, 0.f, 0.f, 0.f};
        for (int i = tid; i < 4160; i += 256) ((f32x4*)s_in)[i] = zz;
    }
    if (EP) s_lab[tid] = lab8[b * HW + y0 * 128 + tid];

    // per-lane global byte offsets for 9 staging rounds (-1 = halo/masked)
    int goff[9];
#pragma unroll
    for (int it = 0; it < 9; ++it) {
        int s = it * 256 + tid;
        int row = s / 520;                  // 130 xslots * 4 ci8
        int rem = s - row * 520;
        int xslot = rem >> 2;
        int ci8 = rem & 3;
        int gy = y0 - 1 + row;
        int gx = xslot - 1;
        bool valid = (s < 2080) && ((unsigned)gy < 128u) && ((unsigned)gx < 128u);
        goff[it] = valid ? (((gy << 7) | gx) * 256 + ci8 * 8) * 2 : -1;
    }

    f32x4 acc[4][8];
#pragma unroll
    for (int i = 0; i < 4; ++i)
#pragma unroll
        for (int j = 0; j < 8; ++j) {
            f32x4 zz = {0.f, 0.f, 0.f, 0.f};
            acc[i][j] = zz;
        }

    const char* src_b = (const char*)(nhwc + (size_t)b * HW * 256);
    const int lane_base = (tid & 192) * 16;     // wave-uniform LDS base
    const f32x4* wa4 = (const f32x4*)wa;

    __syncthreads();                         // order zero ds_writes before glds
#pragma unroll
    for (int it = 0; it < 9; ++it)           // stage chunk 0 -> buf 0
        if (goff[it] >= 0)
            glds16(src_b + goff[it], (char*)s_in + it * 4096 + lane_base);

#pragma unroll 1
    for (int chunk = 0; chunk < 8; ++chunk) {
        __syncthreads();                     // publishes stage(chunk), frees other buf

        // A prefetch (taps 0,1) BEFORE next staging -> older in vmcnt FIFO
        f32x4 a0[4], a1[4];
        {
            int kt8 = chunk * 72;
#pragma unroll
            for (int i = 0; i < 4; ++i) a0[i] = wa4[(kt8 + wc * 4 + i) * 64 + l];
#pragma unroll
            for (int i = 0; i < 4; ++i) a1[i] = wa4[(kt8 + 8 + wc * 4 + i) * 64 + l];
        }
        if (chunk < 7) {                     // stage chunk+1 into other buffer
            char* dstb = (char*)s_in + ((chunk + 1) & 1) * 33280 + lane_base;
#pragma unroll
            for (int it = 0; it < 9; ++it)
                if (goff[it] >= 0)
                    glds16(src_b + goff[it] + (chunk + 1) * 64, dstb + it * 4096);
        }

        const char* bufp = (const char*)s_in + (chunk & 1) * 33280;
#pragma unroll
        for (int tap = 0; tap < 9; ++tap) {
            f32x4 aC[4];
#pragma unroll
            for (int i = 0; i < 4; ++i) aC[i] = a0[i];
#pragma unroll
            for (int i = 0; i < 4; ++i) a0[i] = a1[i];
            if (tap + 2 < 9) {
                int kt8 = chunk * 72 + (tap + 2) * 8;
#pragma unroll
                for (int i = 0; i < 4; ++i)
                    a1[i] = wa4[(kt8 + wc * 4 + i) * 64 + l];
            }
            const int rowi = wr + tap / 3;
            const int dxo = tap % 3;
            f32x4 bf[8];
#pragma unroll
            for (int p = 0; p < 8; ++p) {
                int e = (rowi * 130 + p * 16 + l15 + dxo) * 64 + l16 * 16;
                bf[p] = *(const f32x4*)(bufp + e);
            }
#pragma unroll
            for (int ct = 0; ct < 4; ++ct) {
                bf16x8 av = __builtin_bit_cast(bf16x8, aC[ct]);
#pragma unroll
                for (int p = 0; p < 8; ++p)
                    acc[ct][p] = __builtin_amdgcn_mfma_f32_16x16x32_bf16(
                        av, __builtin_bit_cast(bf16x8, bf[p]), acc[ct][p], 0, 0, 0);
            }
        }
    }

    // D: col = px = l&15, row = co = (l>>4)*4 + reg
    const int y = y0 + wr;
    float* outb = out + (size_t)b * 128 * HW + (size_t)y * 128;
#pragma unroll
    for (int ct = 0; ct < 4; ++ct)
#pragma unroll
        for (int p = 0; p < 8; ++p) {
            int x = p * 16 + l15;
#pragma unroll
            for (int rr = 0; rr < 4; ++rr) {
                int co = wc * 64 + ct * 16 + l16 * 4 + rr;
                outb[(size_t)co * HW + x] = acc[ct][p][rr];
            }
        }

    if (EP) {
        // fuse segment-sum epilogue: reuse s_in (dead) as bins[2][41][129]
        __syncthreads();                     // all waves done reading s_in
        float* binsf = (float*)s_in;         // 2*41*129*4 = 42,312 B <= 66,560
        for (int i = tid; i < 2 * NL * 129; i += 256) binsf[i] = 0.f;
        __syncthreads();
#pragma unroll
        for (int ct = 0; ct < 4; ++ct)
#pragma unroll
            for (int p = 0; p < 8; ++p) {
                int lab = (int)s_lab[wr * 128 + p * 16 + l15];
                float* bp = &binsf[(wr * NL + lab) * 129 + wc * 64 + ct * 16 + l16 * 4];
#pragma unroll
                for (int rr = 0; rr < 4; ++rr)
                    atomicAdd(bp + rr, acc[ct][p][rr]);
            }
        __syncthreads();
        float* pout = pf + (size_t)bid * PSZ;
        for (int i = tid; i < NL * 128; i += 256) {
            int lab = i >> 7, cc = i & 127;
            pout[i] = binsf[lab * 129 + cc] + binsf[(NL + lab) * 129 + cc];
        }
    }
}

// ---------------------------------------------------------------------------
// K_red: sum 64 chunk-partials per (b, lab, c).  grid 328 = b*41+lab.
// addr = b*bstride + lab*128 + c + k*kstride, k = 0..63.
// ---------------------------------------------------------------------------
__global__ __launch_bounds__(128)
void k_red(const float* __restrict__ p, float* __restrict__ sout,
           int bstride, int kstride)
{
    const int bid = (int)blockIdx.x;
    const int b = bid / 41, lab = bid - b * 41;
    const int c = (int)threadIdx.x;
    const float* q = p + (size_t)b * bstride + lab * 128 + c;
    float s = 0.f;
#pragma unroll 8
    for (int k = 0; k < 64; ++k) s += q[(size_t)k * kstride];
    sout[(size_t)bid * 128 + c] = s;
}

// ---------------------------------------------------------------------------
// K_seg_f (fallback when ws too small for pf): fuse-only segment sums,
// one block per (b,c) plane.  grid 1024.
// ---------------------------------------------------------------------------
__global__ __launch_bounds__(256, 3)
void k_seg_f(const float* __restrict__ fuse, const u8* __restrict__ lab8,
             float* __restrict__ sums)
{
    __shared__ float bins[NL][256];         // 41,984 B
    const int bid = (int)blockIdx.x;
    const int c = bid & 127;
    const int b = bid >> 7;
    const int tid = (int)threadIdx.x;

    for (int i = tid; i < NL * 256; i += 256) ((float*)bins)[i] = 0.f;
    __syncthreads();

    const float* src = fuse + ((size_t)(b * 128 + c)) * HW;
    const u8* lp = lab8 + b * HW;

#pragma unroll 4
    for (int k = 0; k < 16; ++k) {
        int i = k * 256 + tid;              // float4 index
        float4 v = ((const float4*)src)[i];
        uchar4 lv = ((const uchar4*)lp)[i];
        bins[lv.x][tid] += v.x;
        bins[lv.y][tid] += v.y;
        bins[lv.z][tid] += v.z;
        bins[lv.w][tid] += v.w;
    }
    __syncthreads();

    for (int stride = 128; stride >= 1; stride >>= 1) {
        for (int idx = tid; idx < NL * stride; idx += 256) {
            int l = idx / stride;
            int cc = idx - l * stride;
            bins[l][cc] += bins[l][cc + stride];
        }
        __syncthreads();
    }
    if (tid < NL)
        sums[(size_t)(b * NL + tid) * 128 + c] = bins[tid][0];
}

// ---------------------------------------------------------------------------
// K3: mean/base select + L2-normalize over classes + SE MLP -> gates.
// sums layout: [feat][b][lab][c] f32.
// ---------------------------------------------------------------------------
__global__ __launch_bounds__(128)
void k_gates(const float* __restrict__ sums, const int* __restrict__ ghist,
             const float* __restrict__ base_f, const float* __restrict__ base_d,
             const float* __restrict__ f_w1, const float* __restrict__ f_w2,
             const float* __restrict__ d_w1, const float* __restrict__ d_w2,
             float* __restrict__ gates)
{
    __shared__ float sv[128];
    __shared__ float h1[8];
    const int b = (int)blockIdx.x >> 1;
    const int feat = (int)blockIdx.x & 1;
    const int c = (int)threadIdx.x;

    const float* base = feat ? base_d : base_f;
    const float* sf = sums + (size_t)feat * 8 * NL * 128;
    float suma = 0.f, sumsq = 0.f;
    for (int lc = 0; lc < NL; ++lc) {
        float s = sf[(size_t)(b * NL + lc) * 128 + c];
        int cnt = ghist[b * NL + lc];
        float att = (cnt > 0) ? (s / (float)cnt) : base[(b * NL + lc) * 128 + c];
        suma += att;
        sumsq += att * att;
    }
    sv[c] = suma / fmaxf(sqrtf(sumsq), 1e-12f);
    __syncthreads();

    const float* w1 = feat ? d_w1 : f_w1;
    const float* w2 = feat ? d_w2 : f_w2;
    if (c < 8) {
        float h = 0.f;
        for (int k = 0; k < 128; ++k) h += w1[c * 128 + k] * sv[k];
        h1[c] = fmaxf(h, 0.f);
    }
    __syncthreads();

    float gv = 0.f;
#pragma unroll
    for (int o = 0; o < 8; ++o) gv += w2[c * 8 + o] * h1[o];
    gates[feat * 1024 + b * 128 + c] = 1.f / (1.f + expf(-gv));
}

// ---------------------------------------------------------------------------
// K4: out = fuse * g_f + d * g_d (fuse in-place in d_out).
// ---------------------------------------------------------------------------
__global__ __launch_bounds__(256)
void k_final(const float* __restrict__ d, const float* __restrict__ gates,
             float* out)
{
    size_t t4 = (size_t)blockIdx.x * 256 + threadIdx.x;
    size_t basei = t4 * 4;
    int bc = (int)(basei >> 14);
    float gf = gates[bc];
    float gd = gates[1024 + bc];
    float4 f = *(const float4*)(out + basei);
    float4 dv = *(const float4*)(d + basei);
    float4 o;
    o.x = f.x * gf + dv.x * gd;
    o.y = f.y * gf + dv.y * gd;
    o.z = f.z * gf + dv.z * gd;
    o.w = f.w * gf + dv.w * gd;
    *(float4*)(out + basei) = o;
}

extern "C" void kernel_launch(void* const* d_in, const int* in_sizes, int n_in,
                              void* d_out, int out_size, void* d_ws, size_t ws_size,
                              hipStream_t stream)
{
    (void)in_sizes; (void)n_in; (void)out_size;
    const float* r      = (const float*)d_in[0];
    const float* d      = (const float*)d_in[1];
    const int*   label  = (const int*)d_in[2];
    const float* conv_w = (const float*)d_in[3];
    const float* f_w1   = (const float*)d_in[4];
    const float* f_w2   = (const float*)d_in[5];
    const float* d_w1   = (const float*)d_in[6];
    const float* d_w2   = (const float*)d_in[7];
    const float* base_f = (const float*)d_in[8];
    const float* base_d = (const float*)d_in[9];
    float* out = (float*)d_out;

    char* ws = (char*)d_ws;
    u16* nhwc    = (u16*)(ws + NHWC_OFF);
    u16* wa      = (u16*)(ws + WA_OFF);
    u8*  lab8    = (u8*)(ws + LAB8_OFF);
    int* ghist   = (int*)(ws + GHIST_OFF);
    float* sums  = (float*)(ws + SUMS_OFF);      // [2][8][41][128]
    float* sums_f = sums;
    float* sums_d = sums + 8 * NL * 128;
    float* gates = (float*)(ws + GATES_OFF);
    float* pf    = (float*)(ws + PF_OFF);        // only if ws is big enough
    float* pd    = (float*)d_out;                // scratch: dead before k_conv

    const bool big = ws_size >= PF_END;

    hipLaunchKernelGGL(k_wpack, dim3(576), dim3(64), 0, stream, conv_w, wa, ghist);
    hipLaunchKernelGGL(k_prep, dim3(512), dim3(256), 0, stream, r, d, label,
                       nhwc, lab8, ghist, pd);
    // reduce d-partials BEFORE k_conv overwrites d_out
    hipLaunchKernelGGL(k_red, dim3(328), dim3(128), 0, stream, pd, sums_d,
                       64 * PSZ, PSZ);
    if (big) {
        hipLaunchKernelGGL(k_conv<1>, dim3(512), dim3(256), 0, stream, nhwc, wa,
                           lab8, out, pf);
        hipLaunchKernelGGL(k_red, dim3(328), dim3(128), 0, stream, pf, sums_f,
                           PSZ, 8 * PSZ);
    } else {
        hipLaunchKernelGGL(k_conv<0>, dim3(512), dim3(256), 0, stream, nhwc, wa,
                           lab8, out, (float*)nullptr);
        hipLaunchKernelGGL(k_seg_f, dim3(1024), dim3(256), 0, stream, out,
                           lab8, sums_f);
    }
    hipLaunchKernelGGL(k_gates, dim3(16), dim3(128), 0, stream, sums, ghist,
                       base_f, base_d, f_w1, f_w2, d_w1, d_w2, gates);
    hipLaunchKernelGGL(k_final, dim3(16384), dim3(256), 0, stream, d, gates, out);
}

// Round 3
// 368.520 us; speedup vs baseline: 1.1666x; 1.1635x over previous
//
#include <hip/hip_runtime.h>
#include <math.h>

typedef unsigned short u16;
typedef unsigned char u8;
typedef unsigned int u32;
typedef unsigned long long u64;
typedef __bf16 bf16x8 __attribute__((ext_vector_type(8)));
typedef float f32x4 __attribute__((ext_vector_type(4)));

#define NL 41
#define HW 16384

// ws layout (bytes) -- PD_END = 78,921,728 < 78,925,824 proven available (r2)
#define NHWC_OFF   0            // 8*16384*256 bf16 = 67,108,864
#define WA_OFF     67108864     // 576*64*8 bf16 = 589,824 -> 67,698,688
#define LAB8_OFF   67698688     // 8*16384 u8 = 131,072 -> 67,829,760
#define SUMS_OFF   67829760     // 2*8*41*128 f32 = 335,872 -> 68,165,632
#define GATES_OFF  68165632     // 2*8*128 f32 = 8,192 -> 68,173,824
#define PD_OFF     68173824     // 512*5248 f32 = 10,747,904 -> 78,921,728
#define PD_END     78921728ull

#define PSZ 5248                // 41*128 per-block partial

__device__ __forceinline__ u16 f2bf(float f) {
    u32 u = __builtin_bit_cast(u32, f);
    u = (u + 0x7FFFu + ((u >> 16) & 1u)) >> 16;
    return (u16)u;
}

__device__ __forceinline__ void glds16(const void* g, void* l) {
    __builtin_amdgcn_global_load_lds(
        (const __attribute__((address_space(1))) void*)g,
        (__attribute__((address_space(3))) void*)l, 16, 0, 0);
}

// ---------------------------------------------------------------------------
// K0: fused add/mul -> bf16 NHWC; labels -> lab8; d-feature segment bins
// (column-per-thread, race/conflict-free, NON-atomic) -> pd[bid][41][128].
// Blocks 0..143 also repack conv weights (absorbed k_wpack: wi = bid*4+tid/64).
// 512 blocks = 8 b x 64 chunks of 256 px.
// ---------------------------------------------------------------------------
__global__ __launch_bounds__(256, 2)
void k_prep(const float* __restrict__ r, const float* __restrict__ d,
            const int* __restrict__ label, const float* __restrict__ w,
            u16* __restrict__ nhwc, u16* __restrict__ wa,
            u8* __restrict__ lab8, float* __restrict__ pd)
{
    __shared__ u16 s[64 * 256];             // [px][c'] 32 KB
    __shared__ float binsd[NL * 256];       // 41,984 B, column tid = (half,c)
    __shared__ u8 s_lab[256];
    const int bid = (int)blockIdx.x;
    const int b = bid >> 6;
    const int px0 = (bid & 63) * 256;
    const int tid = (int)threadIdx.x;
    const int c = tid & 127;
    const int half = tid >> 7;

    // absorbed weight repack (576 virtual 64-lane blocks -> blocks 0..143)
    if (bid < 144) {
        const int wi = bid * 4 + (tid >> 6);
        const int l = tid & 63;
        const int kt = wi >> 3, ct = wi & 7;
        const int chunk = kt / 9, tap = kt - chunk * 9;
        const int co = ct * 16 + (l & 15);
        const int cin0 = chunk * 32 + (l >> 4) * 8;
        u16 tmp[8];
#pragma unroll
        for (int j = 0; j < 8; ++j)
            tmp[j] = f2bf(w[((size_t)co * 256 + cin0 + j) * 9 + tap]);
        *(f32x4*)&wa[((size_t)wi * 64 + l) * 8] = *(f32x4*)tmp;
    }

    for (int i = tid; i < NL * 64; i += 256) ((f32x4*)binsd)[i] = f32x4{0,0,0,0};

    {
        int px = px0 + tid;
        int yy = px >> 7, xx = px & 127;
        int lab = label[(size_t)b * 512 * 512 + (yy * 4) * 512 + xx * 4];
        lab8[b * HW + px] = (u8)lab;
        s_lab[tid] = (u8)lab;
    }
    __syncthreads();                        // s_lab + binsd ready

    for (int t = 0; t < 4; ++t) {
        const int pxb = px0 + t * 64 + half * 32;
        const float* rp = r + ((size_t)(b * 128 + c)) * HW + pxb;
        const float* dp = d + ((size_t)(b * 128 + c)) * HW + pxb;
        const u8* lp = &s_lab[t * 64 + half * 32];
        uint4 lw0 = *(const uint4*)lp;
        uint4 lw1 = *(const uint4*)(lp + 16);
        u32 lwords[8] = {lw0.x, lw0.y, lw0.z, lw0.w, lw1.x, lw1.y, lw1.z, lw1.w};
#pragma unroll
        for (int j = 0; j < 8; ++j) {
            float4 rv = *(const float4*)(rp + j * 4);
            float4 dv = *(const float4*)(dp + j * 4);
            float ra[4] = {rv.x, rv.y, rv.z, rv.w};
            float da[4] = {dv.x, dv.y, dv.z, dv.w};
#pragma unroll
            for (int i = 0; i < 4; ++i) {
                int pxl = half * 32 + j * 4 + i;
                s[pxl * 256 + c] = f2bf(ra[i] + da[i]);
                s[pxl * 256 + 128 + c] = f2bf(ra[i] / (1.f + __expf(-da[i])));
                int lab = (int)((lwords[j] >> (i * 8)) & 0xffu);
                binsd[lab * 256 + tid] += da[i];   // own column: no race
            }
        }
        __syncthreads();
        const f32x4* sf = (const f32x4*)s;
        f32x4* dst = (f32x4*)nhwc + ((size_t)b * HW + px0 + t * 64) * 32;
#pragma unroll
        for (int k = 0; k < 8; ++k) {
            int fi = k * 256 + tid;
            dst[fi] = sf[fi];
        }
        __syncthreads();                    // protect s before next subtile
    }
    // flush d bins -> per-block partials (coalesced, non-atomic)
    float* pout = pd + (size_t)bid * PSZ;
    for (int i = tid; i < NL * 128; i += 256) {
        int lab = i >> 7, cc = i & 127;
        pout[i] = binsd[lab * 256 + cc] + binsd[lab * 256 + 128 + cc];
    }
}

// ---------------------------------------------------------------------------
// K1: conv3x3 implicit GEMM, bf16 MFMA 16x16x32, double-buffered LDS.
// Round-0 proven form (93.9 us, MfmaUtil 34%), no epilogue.
// ---------------------------------------------------------------------------
__global__ __launch_bounds__(256, 2)
void k_conv(const u16* __restrict__ nhwc, const u16* __restrict__ wa,
            float* __restrict__ out)
{
    __shared__ u16 s_in[2 * 2080 * 8];      // 2 x 33280 B
    const int tid = (int)threadIdx.x;
    const int bid = (int)blockIdx.x;
    const int b = bid & 7;
    const int y0 = (bid >> 3) * 2;
    const int l = tid & 63;
    const int wv = tid >> 6;
    const int wr = wv & 1;                  // image row within pair
    const int wc = wv >> 1;                 // co half
    const int l15 = l & 15;
    const int l16 = l >> 4;

    {   // zero BOTH buffers once; halo granules stay zero forever
        f32x4 zz = {0.f, 0.f, 0.f, 0.f};
        for (int i = tid; i < 4160; i += 256) ((f32x4*)s_in)[i] = zz;
    }

    // per-lane global byte offsets for 9 staging rounds (-1 = halo/masked)
    int goff[9];
#pragma unroll
    for (int it = 0; it < 9; ++it) {
        int s = it * 256 + tid;
        int row = s / 520;                  // 130 xslots * 4 ci8
        int rem = s - row * 520;
        int xslot = rem >> 2;
        int ci8 = rem & 3;
        int gy = y0 - 1 + row;
        int gx = xslot - 1;
        bool valid = (s < 2080) && ((unsigned)gy < 128u) && ((unsigned)gx < 128u);
        goff[it] = valid ? (((gy << 7) | gx) * 256 + ci8 * 8) * 2 : -1;
    }

    f32x4 acc[4][8];
#pragma unroll
    for (int i = 0; i < 4; ++i)
#pragma unroll
        for (int j = 0; j < 8; ++j) {
            f32x4 zz = {0.f, 0.f, 0.f, 0.f};
            acc[i][j] = zz;
        }

    const char* src_b = (const char*)(nhwc + (size_t)b * HW * 256);
    const int lane_base = (tid & 192) * 16;     // wave-uniform LDS base
    const f32x4* wa4 = (const f32x4*)wa;

    __syncthreads();                         // order zero ds_writes before glds
#pragma unroll
    for (int it = 0; it < 9; ++it)           // stage chunk 0 -> buf 0
        if (goff[it] >= 0)
            glds16(src_b + goff[it], (char*)s_in + it * 4096 + lane_base);

#pragma unroll 1
    for (int chunk = 0; chunk < 8; ++chunk) {
        __syncthreads();                     // publishes stage(chunk), frees other buf

        // A prefetch (taps 0,1) BEFORE next staging -> older in vmcnt FIFO
        f32x4 a0[4], a1[4];
        {
            int kt8 = chunk * 72;
#pragma unroll
            for (int i = 0; i < 4; ++i) a0[i] = wa4[(kt8 + wc * 4 + i) * 64 + l];
#pragma unroll
            for (int i = 0; i < 4; ++i) a1[i] = wa4[(kt8 + 8 + wc * 4 + i) * 64 + l];
        }
        if (chunk < 7) {                     // stage chunk+1 into other buffer
            char* dstb = (char*)s_in + ((chunk + 1) & 1) * 33280 + lane_base;
#pragma unroll
            for (int it = 0; it < 9; ++it)
                if (goff[it] >= 0)
                    glds16(src_b + goff[it] + (chunk + 1) * 64, dstb + it * 4096);
        }

        const char* bufp = (const char*)s_in + (chunk & 1) * 33280;
#pragma unroll
        for (int tap = 0; tap < 9; ++tap) {
            f32x4 aC[4];
#pragma unroll
            for (int i = 0; i < 4; ++i) aC[i] = a0[i];
#pragma unroll
            for (int i = 0; i < 4; ++i) a0[i] = a1[i];
            if (tap + 2 < 9) {
                int kt8 = chunk * 72 + (tap + 2) * 8;
#pragma unroll
                for (int i = 0; i < 4; ++i)
                    a1[i] = wa4[(kt8 + wc * 4 + i) * 64 + l];
            }
            const int rowi = wr + tap / 3;
            const int dxo = tap % 3;
            f32x4 bf[8];
#pragma unroll
            for (int p = 0; p < 8; ++p) {
                int e = (rowi * 130 + p * 16 + l15 + dxo) * 64 + l16 * 16;
                bf[p] = *(const f32x4*)(bufp + e);
            }
#pragma unroll
            for (int ct = 0; ct < 4; ++ct) {
                bf16x8 av = __builtin_bit_cast(bf16x8, aC[ct]);
#pragma unroll
                for (int p = 0; p < 8; ++p)
                    acc[ct][p] = __builtin_amdgcn_mfma_f32_16x16x32_bf16(
                        av, __builtin_bit_cast(bf16x8, bf[p]), acc[ct][p], 0, 0, 0);
            }
        }
    }

    // D: col = px = l&15, row = co = (l>>4)*4 + reg
    const int y = y0 + wr;
    float* outb = out + (size_t)b * 128 * HW + (size_t)y * 128;
#pragma unroll
    for (int ct = 0; ct < 4; ++ct)
#pragma unroll
        for (int p = 0; p < 8; ++p) {
            int x = p * 16 + l15;
#pragma unroll
            for (int rr = 0; rr < 4; ++rr) {
                int co = wc * 64 + ct * 16 + l16 * 4 + rr;
                outb[(size_t)co * HW + x] = acc[ct][p][rr];
            }
        }
}

// ---------------------------------------------------------------------------
// K2: bid<1024: fuse segment sums, one (b,c) plane per block (round-0 proven
// column-per-thread structure, no atomics) -> sums_f.
// bid>=1024 (328 blocks): reduce pd chunk-partials -> sums_d.
// ---------------------------------------------------------------------------
__global__ __launch_bounds__(256, 3)
void k_seg2(const float* __restrict__ fuse, const float* __restrict__ pd,
            const u8* __restrict__ lab8, float* __restrict__ sums_f,
            float* __restrict__ sums_d)
{
    __shared__ float bins[NL][256];         // 41,984 B
    const int bid = (int)blockIdx.x;
    const int tid = (int)threadIdx.x;

    if (bid >= 1024) {                      // d-partial reduction
        const int idx = bid - 1024;         // b*41 + lab
        if (tid < 128) {
            const int b = idx / 41, lab = idx - b * 41;
            const float* q = pd + (size_t)b * 64 * PSZ + lab * 128 + tid;
            float sv = 0.f;
#pragma unroll 8
            for (int k = 0; k < 64; ++k) sv += q[(size_t)k * PSZ];
            sums_d[(size_t)idx * 128 + tid] = sv;
        }
        return;
    }

    const int c = bid & 127;
    const int b = bid >> 7;

    for (int i = tid; i < NL * 256; i += 256) ((float*)bins)[i] = 0.f;
    __syncthreads();

    const float* src = fuse + ((size_t)(b * 128 + c)) * HW;
    const u8* lp = lab8 + b * HW;

#pragma unroll 4
    for (int k = 0; k < 16; ++k) {
        int i = k * 256 + tid;              // float4 index
        float4 v = ((const float4*)src)[i];
        uchar4 lv = ((const uchar4*)lp)[i];
        bins[lv.x][tid] += v.x;
        bins[lv.y][tid] += v.y;
        bins[lv.z][tid] += v.z;
        bins[lv.w][tid] += v.w;
    }
    __syncthreads();

    for (int stride = 128; stride >= 1; stride >>= 1) {
        for (int idx = tid; idx < NL * stride; idx += 256) {
            int l = idx / stride;
            int cc = idx - l * stride;
            bins[l][cc] += bins[l][cc + stride];
        }
        __syncthreads();
    }
    if (tid < NL)
        sums_f[(size_t)(b * NL + tid) * 128 + c] = bins[tid][0];
}

// ---------------------------------------------------------------------------
// K3: counts from lab8 (tiny LDS hist) + mean/base select + L2-normalize over
// classes + SE MLP -> gates.  16 blocks = (b, feat).
// ---------------------------------------------------------------------------
__global__ __launch_bounds__(128)
void k_gates(const float* __restrict__ sums, const u8* __restrict__ lab8,
             const float* __restrict__ base_f, const float* __restrict__ base_d,
             const float* __restrict__ f_w1, const float* __restrict__ f_w2,
             const float* __restrict__ d_w1, const float* __restrict__ d_w2,
             float* __restrict__ gates)
{
    __shared__ float sv[128];
    __shared__ float h1[8];
    __shared__ int hist[NL];
    const int b = (int)blockIdx.x >> 1;
    const int feat = (int)blockIdx.x & 1;
    const int c = (int)threadIdx.x;

    if (c < NL) hist[c] = 0;
    __syncthreads();
    {   // histogram 16384 labels, uchar4 loads, 128 LDS atomics/thread
        const uchar4* lp = (const uchar4*)(lab8 + (size_t)b * HW);
        for (int k = 0; k < 32; ++k) {
            uchar4 lv = lp[c + k * 128];
            atomicAdd(&hist[lv.x], 1);
            atomicAdd(&hist[lv.y], 1);
            atomicAdd(&hist[lv.z], 1);
            atomicAdd(&hist[lv.w], 1);
        }
    }
    __syncthreads();

    const float* base = feat ? base_d : base_f;
    const float* sf = sums + (size_t)feat * 8 * NL * 128;
    float suma = 0.f, sumsq = 0.f;
    for (int lc = 0; lc < NL; ++lc) {
        float s = sf[(size_t)(b * NL + lc) * 128 + c];
        int cnt = hist[lc];
        float att = (cnt > 0) ? (s / (float)cnt) : base[(b * NL + lc) * 128 + c];
        suma += att;
        sumsq += att * att;
    }
    sv[c] = suma / fmaxf(sqrtf(sumsq), 1e-12f);
    __syncthreads();

    const float* w1 = feat ? d_w1 : f_w1;
    const float* w2 = feat ? d_w2 : f_w2;
    if (c < 8) {
        float h = 0.f;
        for (int k = 0; k < 128; ++k) h += w1[c * 128 + k] * sv[k];
        h1[c] = fmaxf(h, 0.f);
    }
    __syncthreads();

    float gv = 0.f;
#pragma unroll
    for (int o = 0; o < 8; ++o) gv += w2[c * 8 + o] * h1[o];
    gates[feat * 1024 + b * 128 + c] = 1.f / (1.f + expf(-gv));
}

// ---------------------------------------------------------------------------
// K4: out = fuse * g_f + d * g_d (fuse in-place in d_out). Grid-stride, 2048
// blocks (G11: cap grid, fewer dispatch slots).
// ---------------------------------------------------------------------------
__global__ __launch_bounds__(256)
void k_final(const float* __restrict__ d, const float* __restrict__ gates,
             float* out)
{
    const size_t base = (size_t)blockIdx.x * 256 + threadIdx.x;
#pragma unroll
    for (int it = 0; it < 8; ++it) {
        size_t t4 = base + (size_t)it * (2048 * 256);
        size_t basei = t4 * 4;
        int bc = (int)(basei >> 14);
        float gf = gates[bc];
        float gd = gates[1024 + bc];
        float4 f = *(const float4*)(out + basei);
        float4 dv = *(const float4*)(d + basei);
        float4 o;
        o.x = f.x * gf + dv.x * gd;
        o.y = f.y * gf + dv.y * gd;
        o.z = f.z * gf + dv.z * gd;
        o.w = f.w * gf + dv.w * gd;
        *(float4*)(out + basei) = o;
    }
}

// ---------------------------------------------------------------------------
// Fallback reducer (only if ws smaller than PD_END): pd lives in d_out, must
// reduce before k_conv overwrites it.
// ---------------------------------------------------------------------------
__global__ __launch_bounds__(128)
void k_red(const float* __restrict__ p, float* __restrict__ sout)
{
    const int bid = (int)blockIdx.x;
    const int b = bid / 41, lab = bid - b * 41;
    const int c = (int)threadIdx.x;
    const float* q = p + (size_t)b * 64 * PSZ + lab * 128 + c;
    float s = 0.f;
#pragma unroll 8
    for (int k = 0; k < 64; ++k) s += q[(size_t)k * PSZ];
    sout[(size_t)bid * 128 + c] = s;
}

extern "C" void kernel_launch(void* const* d_in, const int* in_sizes, int n_in,
                              void* d_out, int out_size, void* d_ws, size_t ws_size,
                              hipStream_t stream)
{
    (void)in_sizes; (void)n_in; (void)out_size;
    const float* r      = (const float*)d_in[0];
    const float* d      = (const float*)d_in[1];
    const int*   label  = (const int*)d_in[2];
    const float* conv_w = (const float*)d_in[3];
    const float* f_w1   = (const float*)d_in[4];
    const float* f_w2   = (const float*)d_in[5];
    const float* d_w1   = (const float*)d_in[6];
    const float* d_w2   = (const float*)d_in[7];
    const float* base_f = (const float*)d_in[8];
    const float* base_d = (const float*)d_in[9];
    float* out = (float*)d_out;

    char* ws = (char*)d_ws;
    u16* nhwc     = (u16*)(ws + NHWC_OFF);
    u16* wa       = (u16*)(ws + WA_OFF);
    u8*  lab8     = (u8*)(ws + LAB8_OFF);
    float* sums   = (float*)(ws + SUMS_OFF);     // [2][8][41][128]
    float* sums_f = sums;
    float* sums_d = sums + 8 * NL * 128;
    float* gates  = (float*)(ws + GATES_OFF);

    const bool big = ws_size >= PD_END;          // proven true by r2 big-path
    float* pd = big ? (float*)(ws + PD_OFF) : (float*)d_out;

    hipLaunchKernelGGL(k_prep, dim3(512), dim3(256), 0, stream, r, d, label,
                       conv_w, nhwc, wa, lab8, pd);
    if (!big)   // pd in d_out: reduce before k_conv clobbers it
        hipLaunchKernelGGL(k_red, dim3(328), dim3(128), 0, stream, pd, sums_d);
    hipLaunchKernelGGL(k_conv, dim3(512), dim3(256), 0, stream, nhwc, wa, out);
    hipLaunchKernelGGL(k_seg2, dim3(big ? 1352 : 1024), dim3(256), 0, stream,
                       out, pd, lab8, sums_f, sums_d);
    hipLaunchKernelGGL(k_gates, dim3(16), dim3(128), 0, stream, sums, lab8,
                       base_f, base_d, f_w1, f_w2, d_w1, d_w2, gates);
    hipLaunchKernelGGL(k_final, dim3(2048), dim3(256), 0, stream, d, gates, out);
}